// Round 1
// baseline (147.420 us; speedup 1.0000x reference)
//
#include <hip/hip_runtime.h>

#define HH 3500
#define WW 2500

__global__ __launch_bounds__(256) void st_warp_kernel(
    const float* __restrict__ src,   // [3, H, W]
    const float* __restrict__ flow,  // [2, H, W]
    float* __restrict__ out)         // [3*H*W] warped ++ [H*W*2] norm_grid
{
    const int x = blockIdx.x * blockDim.x + threadIdx.x;
    const int y = blockIdx.y;
    if (x >= WW) return;

    const long HW = (long)HH * WW;
    const long idx = (long)y * WW + x;

    const float fx = flow[idx];
    const float fy = flow[HW + idx];

    const float gx = fx + (float)x;
    const float gy = fy + (float)y;

    const float nx = 2.0f * gx / (float)(WW - 1) - 1.0f;
    const float ny = 2.0f * gy / (float)(HH - 1) - 1.0f;

    // second output: norm_grid [H, W, 2] interleaved
    float2* ng = (float2*)(out + 3 * HW);
    ng[idx] = make_float2(nx, ny);

    // un-normalize (replicates reference numerics exactly)
    const float ix = (nx + 1.0f) * 0.5f * (float)(WW - 1);
    const float iy = (ny + 1.0f) * 0.5f * (float)(HH - 1);

    const float x0f = floorf(ix);
    const float y0f = floorf(iy);
    const float wx1 = ix - x0f, wx0 = 1.0f - wx1;
    const float wy1 = iy - y0f, wy0 = 1.0f - wy1;

    const int x0 = (int)x0f, y0 = (int)y0f;
    const int x1 = x0 + 1,  y1 = y0 + 1;

    const bool vx0 = (x0 >= 0) & (x0 <= WW - 1);
    const bool vx1 = (x1 >= 0) & (x1 <= WW - 1);
    const bool vy0 = (y0 >= 0) & (y0 <= HH - 1);
    const bool vy1 = (y1 >= 0) & (y1 <= HH - 1);

    const int x0c = min(max(x0, 0), WW - 1);
    const int x1c = min(max(x1, 0), WW - 1);
    const int y0c = min(max(y0, 0), HH - 1);
    const int y1c = min(max(y1, 0), HH - 1);

    const float w00 = wx0 * wy0 * ((vx0 & vy0) ? 1.0f : 0.0f);
    const float w10 = wx1 * wy0 * ((vx1 & vy0) ? 1.0f : 0.0f);
    const float w01 = wx0 * wy1 * ((vx0 & vy1) ? 1.0f : 0.0f);
    const float w11 = wx1 * wy1 * ((vx1 & vy1) ? 1.0f : 0.0f);

    const long off00 = (long)y0c * WW + x0c;
    const long off10 = (long)y0c * WW + x1c;
    const long off01 = (long)y1c * WW + x0c;
    const long off11 = (long)y1c * WW + x1c;

#pragma unroll
    for (int c = 0; c < 3; ++c) {
        const float* __restrict__ s = src + (long)c * HW;
        const float v = s[off00] * w00 + s[off10] * w10
                      + s[off01] * w01 + s[off11] * w11;
        out[(long)c * HW + idx] = v;
    }
}

extern "C" void kernel_launch(void* const* d_in, const int* in_sizes, int n_in,
                              void* d_out, int out_size, void* d_ws, size_t ws_size,
                              hipStream_t stream) {
    const float* src  = (const float*)d_in[0];
    const float* flow = (const float*)d_in[1];
    float* out = (float*)d_out;

    dim3 block(256, 1, 1);
    dim3 grid((WW + 255) / 256, HH, 1);
    st_warp_kernel<<<grid, block, 0, stream>>>(src, flow, out);
}

// Round 2
// 142.889 us; speedup vs baseline: 1.0317x; 1.0317x over previous
//
#include <hip/hip_runtime.h>

#define HH 3500
#define WW 2500
#define TXs 64
#define TYs 16
#define RAD 8
#define WIN_H (TYs + 2*RAD + 1)   // 33 rows
#define WIN_W 84                  // 81 cols rounded up to 21 float4s
#define WIN_W4 (WIN_W/4)          // 21
#define NTX ((WW + TXs - 1)/TXs)  // 40
#define NTY ((HH + TYs - 1)/TYs)  // 219
#define NXCD 8

__global__ __launch_bounds__(256) void st_warp_tiled(
    const float* __restrict__ src,   // [3, H, W]
    const float* __restrict__ flow,  // [2, H, W]
    float* __restrict__ out)         // [3*H*W] warped ++ [H*W*2] norm_grid
{
    __shared__ float sm[3][WIN_H][WIN_W];

    const int nwg = NTX * NTY;          // 8760, divisible by 8
    const int cpx = nwg / NXCD;         // 1095
    const int bid = blockIdx.x;
    const int sbid = (bid % NXCD) * cpx + bid / NXCD;  // XCD-chunked, bijective
    const int xt = sbid / NTY;          // column-major: vertical neighbors adjacent
    const int yt = sbid - xt * NTY;

    const int tx0 = xt * TXs;
    const int ty0 = yt * TYs;
    const int cx0 = tx0 - RAD;          // multiple of 4 -> 16B-aligned source cols
    const int ry0 = ty0 - RAD;

    const long HW = (long)HH * WW;
    const int tid = threadIdx.x;

    // ---- stage src halo window into LDS ----
    const bool colsafe = (cx0 >= 0) && (cx0 + WIN_W <= WW);
    if (colsafe) {
#pragma unroll
        for (int e0 = 0; e0 < 3*WIN_H*WIN_W4; e0 += 256) {
            const int e = e0 + tid;
            if (e < 3*WIN_H*WIN_W4) {
                const int c   = e / (WIN_H*WIN_W4);
                const int rem = e - c*(WIN_H*WIN_W4);
                const int r   = rem / WIN_W4;
                const int v   = rem - r*WIN_W4;
                int gy = ry0 + r; gy = min(max(gy, 0), HH-1);
                const float4 val = *reinterpret_cast<const float4*>(
                    src + (long)c*HW + (long)gy*WW + (cx0 + 4*v));
                *reinterpret_cast<float4*>(&sm[c][r][4*v]) = val;
            }
        }
    } else {
        for (int e = tid; e < 3*WIN_H*WIN_W; e += 256) {
            const int c   = e / (WIN_H*WIN_W);
            const int rem = e - c*(WIN_H*WIN_W);
            const int r   = rem / WIN_W;
            const int j   = rem - r*WIN_W;
            int gy = ry0 + r; gy = min(max(gy, 0), HH-1);
            int gx = cx0 + j; gx = min(max(gx, 0), WW-1);
            sm[c][r][j] = src[(long)c*HW + (long)gy*WW + gx];
        }
    }
    __syncthreads();

    const int tidx = tid & 63;
    const int tidy = tid >> 6;
    const int x = tx0 + tidx;
    if (x >= WW) return;  // no barriers below

    float2* ng = (float2*)(out + 3*HW);

#pragma unroll
    for (int k = 0; k < 4; ++k) {
        const int y = ty0 + tidy*4 + k;
        if (y >= HH) continue;

        const long idx = (long)y*WW + x;
        const float fx = flow[idx];
        const float fy = flow[HW + idx];

        const float gx = fx + (float)x;
        const float gy = fy + (float)y;

        const float nx = 2.0f * gx / (float)(WW-1) - 1.0f;
        const float ny = 2.0f * gy / (float)(HH-1) - 1.0f;
        ng[idx] = make_float2(nx, ny);

        // un-normalize exactly as reference (round-trip preserved)
        const float ixp = (nx + 1.0f) * 0.5f * (float)(WW-1);
        const float iyp = (ny + 1.0f) * 0.5f * (float)(HH-1);

        const float x0f = floorf(ixp), y0f = floorf(iyp);
        const float wx1 = ixp - x0f, wx0 = 1.0f - wx1;
        const float wy1 = iyp - y0f, wy0 = 1.0f - wy1;

        const int x0 = (int)x0f, y0 = (int)y0f;
        const int x1 = x0 + 1,  y1 = y0 + 1;

        const bool vx0 = (x0 >= 0) & (x0 < WW);
        const bool vx1 = (x1 >= 0) & (x1 < WW);
        const bool vy0 = (y0 >= 0) & (y0 < HH);
        const bool vy1 = (y1 >= 0) & (y1 < HH);

        const float w00 = wx0*wy0*((vx0 & vy0) ? 1.0f : 0.0f);
        const float w10 = wx1*wy0*((vx1 & vy0) ? 1.0f : 0.0f);
        const float w01 = wx0*wy1*((vx0 & vy1) ? 1.0f : 0.0f);
        const float w11 = wx1*wy1*((vx1 & vy1) ? 1.0f : 0.0f);

        const int x0c = min(max(x0, 0), WW-1);
        const int x1c = min(max(x1, 0), WW-1);
        const int y0c = min(max(y0, 0), HH-1);
        const int y1c = min(max(y1, 0), HH-1);

        const bool inwin = (x0 >= cx0) & (x1 <= cx0 + WIN_W - 1) &
                           (y0 >= ry0) & (y1 <= ry0 + WIN_H - 1);

        if (inwin) {
            const int lx0 = x0c - cx0, lx1 = x1c - cx0;
            const int ly0 = y0c - ry0, ly1 = y1c - ry0;
#pragma unroll
            for (int c = 0; c < 3; ++c) {
                const float v = sm[c][ly0][lx0]*w00 + sm[c][ly0][lx1]*w10
                              + sm[c][ly1][lx0]*w01 + sm[c][ly1][lx1]*w11;
                out[(long)c*HW + idx] = v;
            }
        } else {
            const long off00 = (long)y0c*WW + x0c;
            const long off10 = (long)y0c*WW + x1c;
            const long off01 = (long)y1c*WW + x0c;
            const long off11 = (long)y1c*WW + x1c;
#pragma unroll
            for (int c = 0; c < 3; ++c) {
                const float* __restrict__ s = src + (long)c*HW;
                const float v = s[off00]*w00 + s[off10]*w10
                              + s[off01]*w01 + s[off11]*w11;
                out[(long)c*HW + idx] = v;
            }
        }
    }
}

extern "C" void kernel_launch(void* const* d_in, const int* in_sizes, int n_in,
                              void* d_out, int out_size, void* d_ws, size_t ws_size,
                              hipStream_t stream) {
    const float* src  = (const float*)d_in[0];
    const float* flow = (const float*)d_in[1];
    float* out = (float*)d_out;
    (void)d_ws; (void)ws_size; (void)in_sizes; (void)n_in; (void)out_size;

    dim3 block(256, 1, 1);
    dim3 grid(NTX * NTY, 1, 1);
    st_warp_tiled<<<grid, block, 0, stream>>>(src, flow, out);
}

// Round 4
// 113.297 us; speedup vs baseline: 1.3012x; 1.2612x over previous
//
#include <hip/hip_runtime.h>

#define HH 3500
#define WW 2500
#define TXs 64
#define TYs 16
#define WIN_H 32                  // rows ry0 .. ry0+31  (fy in [-8, ~8))
#define WIN_W 84                  // cols cx0 .. cx0+83, 21 float4s
#define WIN_W4 (WIN_W/4)
#define NTX ((WW + TXs - 1)/TXs)  // 40
#define NTY ((HH + TYs - 1)/TYs)  // 219
#define NXCD 8

typedef float f32x4 __attribute__((ext_vector_type(4)));

__global__ __launch_bounds__(256, 5) void st_warp_v4(
    const float* __restrict__ src,   // [3, H, W]
    const float* __restrict__ flow,  // [2, H, W]
    float* __restrict__ out)         // [3*H*W] warped ++ [H*W*2] norm_grid
{
    __shared__ float sm[3][WIN_H][WIN_W];   // 32,256 B -> 5 blocks/CU

    const int nwg = NTX * NTY;              // 8760 (div by 8)
    const int cpx = nwg / NXCD;
    const int bid = blockIdx.x;
    const int sbid = (bid % NXCD) * cpx + bid / NXCD;  // bijective XCD chunking
    const int xt = sbid / NTY;              // column-major tile order
    const int yt = sbid - xt * NTY;

    const int tx0 = xt * TXs;
    const int ty0 = yt * TYs;
    const int cx0 = tx0 - 8;                // mult of 4 -> 16B-aligned staging
    const int ry0 = ty0 - 8;

    const long HW = (long)HH * WW;
    const int tid = threadIdx.x;

    // ---- stage src halo window into LDS (float4, coalesced) ----
    const bool colsafe = (cx0 >= 0) && (cx0 + WIN_W <= WW);
    if (colsafe) {
#pragma unroll
        for (int e0 = 0; e0 < 3*WIN_H*WIN_W4; e0 += 256) {
            const int e = e0 + tid;
            if (e < 3*WIN_H*WIN_W4) {
                const int c   = e / (WIN_H*WIN_W4);
                const int rem = e - c*(WIN_H*WIN_W4);
                const int r   = rem / WIN_W4;
                const int v   = rem - r*WIN_W4;
                int gy = ry0 + r; gy = min(max(gy, 0), HH-1);
                const f32x4 val = *reinterpret_cast<const f32x4*>(
                    src + (long)c*HW + (long)gy*WW + (cx0 + 4*v));
                *reinterpret_cast<f32x4*>(&sm[c][r][4*v]) = val;
            }
        }
    } else {
        for (int e = tid; e < 3*WIN_H*WIN_W; e += 256) {
            const int c   = e / (WIN_H*WIN_W);
            const int rem = e - c*(WIN_H*WIN_W);
            const int r   = rem / WIN_W;
            const int j   = rem - r*WIN_W;
            int gy = ry0 + r; gy = min(max(gy, 0), HH-1);
            int gx = cx0 + j; gx = min(max(gx, 0), WW-1);
            sm[c][r][j] = src[(long)c*HW + (long)gy*WW + gx];
        }
    }
    __syncthreads();

    // ---- each thread: 4 consecutive x pixels in one row ----
    const int r  = tid >> 4;                 // 0..15
    const int xb = tx0 + (tid & 15) * 4;     // 16B-aligned pixel quad
    const int y  = ty0 + r;
    if (xb >= WW || y >= HH) return;         // quads are all-in or all-out (WW%4==0)

    const long idx = (long)y * WW + xb;
    const f32x4 fx4 = *reinterpret_cast<const f32x4*>(flow + idx);
    const f32x4 fy4 = *reinterpret_cast<const f32x4*>(flow + HW + idx);

    float o[3][4];
    float ngv[8];

#pragma unroll
    for (int k = 0; k < 4; ++k) {
        const int x = xb + k;
        const float gx = fx4[k] + (float)x;
        const float gy = fy4[k] + (float)y;

        const float nx = 2.0f * gx / (float)(WW-1) - 1.0f;
        const float ny = 2.0f * gy / (float)(HH-1) - 1.0f;
        ngv[2*k]   = nx;
        ngv[2*k+1] = ny;

        // un-normalize exactly as reference (round-trip preserved)
        const float ixp = (nx + 1.0f) * 0.5f * (float)(WW-1);
        const float iyp = (ny + 1.0f) * 0.5f * (float)(HH-1);

        const float x0f = floorf(ixp), y0f = floorf(iyp);
        const float wx1 = ixp - x0f, wx0 = 1.0f - wx1;
        const float wy1 = iyp - y0f, wy0 = 1.0f - wy1;

        const int x0 = (int)x0f, y0i = (int)y0f;
        const int x1 = x0 + 1,  y1i = y0i + 1;

        const bool vx0 = (x0  >= 0) & (x0  < WW);
        const bool vx1 = (x1  >= 0) & (x1  < WW);
        const bool vy0 = (y0i >= 0) & (y0i < HH);
        const bool vy1 = (y1i >= 0) & (y1i < HH);

        const float w00 = wx0*wy0*((vx0 & vy0) ? 1.0f : 0.0f);
        const float w10 = wx1*wy0*((vx1 & vy0) ? 1.0f : 0.0f);
        const float w01 = wx0*wy1*((vx0 & vy1) ? 1.0f : 0.0f);
        const float w11 = wx1*wy1*((vx1 & vy1) ? 1.0f : 0.0f);

        const int x0c = min(max(x0,  0), WW-1);
        const int x1c = min(max(x1,  0), WW-1);
        const int y0c = min(max(y0i, 0), HH-1);
        const int y1c = min(max(y1i, 0), HH-1);

        const bool inwin = (x0 >= cx0) & (x1 <= cx0 + WIN_W - 1) &
                           (y0i >= ry0) & (y1i <= ry0 + WIN_H - 1);

        if (inwin) {
            const int lx0 = x0c - cx0, lx1 = x1c - cx0;
            const int ly0 = y0c - ry0, ly1 = y1c - ry0;
#pragma unroll
            for (int c = 0; c < 3; ++c) {
                o[c][k] = sm[c][ly0][lx0]*w00 + sm[c][ly0][lx1]*w10
                        + sm[c][ly1][lx0]*w01 + sm[c][ly1][lx1]*w11;
            }
        } else {
            const long off00 = (long)y0c*WW + x0c;
            const long off10 = (long)y0c*WW + x1c;
            const long off01 = (long)y1c*WW + x0c;
            const long off11 = (long)y1c*WW + x1c;
#pragma unroll
            for (int c = 0; c < 3; ++c) {
                const float* __restrict__ s = src + (long)c*HW;
                o[c][k] = s[off00]*w00 + s[off10]*w10
                        + s[off01]*w01 + s[off11]*w11;
            }
        }
    }

    // ---- vectorized, nontemporal stores (outputs never re-read) ----
#pragma unroll
    for (int c = 0; c < 3; ++c) {
        f32x4 v = {o[c][0], o[c][1], o[c][2], o[c][3]};
        __builtin_nontemporal_store(v, reinterpret_cast<f32x4*>(out + (long)c*HW + idx));
    }
    float* ngbase = out + 3*HW + 2*idx;     // [H, W, 2] interleaved
    f32x4 n0 = {ngv[0], ngv[1], ngv[2], ngv[3]};
    f32x4 n1 = {ngv[4], ngv[5], ngv[6], ngv[7]};
    __builtin_nontemporal_store(n0, reinterpret_cast<f32x4*>(ngbase));
    __builtin_nontemporal_store(n1, reinterpret_cast<f32x4*>(ngbase + 4));
}

extern "C" void kernel_launch(void* const* d_in, const int* in_sizes, int n_in,
                              void* d_out, int out_size, void* d_ws, size_t ws_size,
                              hipStream_t stream) {
    const float* src  = (const float*)d_in[0];
    const float* flow = (const float*)d_in[1];
    float* out = (float*)d_out;
    (void)d_ws; (void)ws_size; (void)in_sizes; (void)n_in; (void)out_size;

    dim3 block(256, 1, 1);
    dim3 grid(NTX * NTY, 1, 1);
    st_warp_v4<<<grid, block, 0, stream>>>(src, flow, out);
}